// Round 2
// baseline (537.195 us; speedup 1.0000x reference)
//
#include <hip/hip_runtime.h>
#include <stdint.h>

typedef __bf16 bf16_t;
typedef __bf16 bf16x4 __attribute__((ext_vector_type(4)));
typedef __bf16 bf16x8 __attribute__((ext_vector_type(8)));
typedef float  f32x4  __attribute__((ext_vector_type(4)));

typedef __attribute__((address_space(1))) const uint32_t gas_u32;
typedef __attribute__((address_space(3))) uint32_t las_u32;

#define MFMA16(a, b, c) __builtin_amdgcn_mfma_f32_16x16x32_bf16((a), (b), (c), 0, 0, 0)

__device__ __forceinline__ void gl_lds16(const bf16_t* g, bf16_t* l) {
    __builtin_amdgcn_global_load_lds((gas_u32*)g, (las_u32*)l, 16, 0, 0);
}

// ---------------------------------------------------------------------------
// fp32 -> bf16 elementwise cast, 8 elem/thread.
// ---------------------------------------------------------------------------
__global__ __launch_bounds__(256) void castbf(const float* __restrict__ X,
                                              bf16_t* __restrict__ Xb)
{
    size_t i = ((size_t)blockIdx.x * 256 + threadIdx.x) * 8;
    float4 a = *(const float4*)&X[i];
    float4 b = *(const float4*)&X[i + 4];
    bf16x8 o;
    o[0] = (bf16_t)a.x; o[1] = (bf16_t)a.y; o[2] = (bf16_t)a.z; o[3] = (bf16_t)a.w;
    o[4] = (bf16_t)b.x; o[5] = (bf16_t)b.y; o[6] = (bf16_t)b.z; o[7] = (bf16_t)b.w;
    *(bf16x8*)&Xb[i] = o;
}

// ---------------------------------------------------------------------------
// Transpose+cast 1024x1024 fp32 weights -> bf16: O[c][r] = W[r][c].
// grid (16,16,4), 256 thr.
// ---------------------------------------------------------------------------
__global__ __launch_bounds__(256) void ktrans(
    const float* __restrict__ W0, const float* __restrict__ W1,
    const float* __restrict__ W2, const float* __restrict__ W3,
    bf16_t* __restrict__ WT)
{
    __shared__ float t[64 * 68];
    const int z = blockIdx.z;
    const float* W = (z == 0) ? W0 : (z == 1) ? W1 : (z == 2) ? W2 : W3;
    bf16_t* O = WT + (size_t)z * 1024 * 1024;
    const int r0 = blockIdx.y * 64, c0 = blockIdx.x * 64;
    const int tid = threadIdx.x;
    const int row = tid >> 2, colg = (tid & 3) * 16;
#pragma unroll
    for (int p = 0; p < 4; ++p)
        *(float4*)&t[row * 68 + colg + p * 4] =
            *(const float4*)&W[(size_t)(r0 + row) * 1024 + c0 + colg + p * 4];
    __syncthreads();
    bf16x8 v0, v1;
#pragma unroll
    for (int j = 0; j < 8; ++j) {
        v0[j] = (bf16_t)t[(colg + j) * 68 + row];
        v1[j] = (bf16_t)t[(colg + 8 + j) * 68 + row];
    }
    *(bf16x8*)&O[(size_t)(c0 + row) * 1024 + r0 + colg] = v0;
    *(bf16x8*)&O[(size_t)(c0 + row) * 1024 + r0 + colg + 8] = v1;
}

// ---------------------------------------------------------------------------
// C = A(MxK) * Bt(NxK)^T + bias(fp32), bf16 in, fp32 accum, OutT out.
// m97 structure: global_load_lds x4 + 8 ds_read_b128 + 16 MFMA per K-iter.
// ---------------------------------------------------------------------------
template <typename OutT>
__global__ __launch_bounds__(256) void gemm_bt(
    const bf16_t* __restrict__ A, const bf16_t* __restrict__ Bt,
    const float* __restrict__ bias, OutT* __restrict__ C,
    int M, int N, int K)
{
    __shared__ bf16_t As[128 * 32];
    __shared__ bf16_t Bs[128 * 32];
    const int tid = threadIdx.x;
    const int lane = tid & 63, wave = tid >> 6;
    const int q = lane >> 4, ln = lane & 15;
    const int m0 = blockIdx.x * 128, n0 = blockIdx.y * 128;
    const int wm = (wave >> 1) * 64, wn = (wave & 1) * 64;
    const int srow = tid >> 2, scol = (tid & 3) * 8;

    f32x4 acc[4][4] = {};
    const bf16_t* Ag = A + (size_t)(m0 + srow) * K + scol;
    const bf16_t* Bg = Bt + (size_t)(n0 + srow) * K + scol;
    bf16_t* Al = As + srow * 32 + scol;
    bf16_t* Bl = Bs + srow * 32 + scol;

    for (int k0 = 0; k0 < K; k0 += 32) {
        __syncthreads();
        gl_lds16(Ag + k0, Al);
        gl_lds16(Ag + k0 + (size_t)64 * K, Al + 64 * 32);
        gl_lds16(Bg + k0, Bl);
        gl_lds16(Bg + k0 + (size_t)64 * K, Bl + 64 * 32);
        __syncthreads();
        bf16x8 a[4], b[4];
#pragma unroll
        for (int mt = 0; mt < 4; ++mt)
            a[mt] = *(const bf16x8*)&As[(wm + mt * 16 + ln) * 32 + q * 8];
#pragma unroll
        for (int nt = 0; nt < 4; ++nt)
            b[nt] = *(const bf16x8*)&Bs[(wn + nt * 16 + ln) * 32 + q * 8];
#pragma unroll
        for (int mt = 0; mt < 4; ++mt)
#pragma unroll
            for (int nt = 0; nt < 4; ++nt)
                acc[mt][nt] = MFMA16(a[mt], b[nt], acc[mt][nt]);
    }
#pragma unroll
    for (int nt = 0; nt < 4; ++nt) {
        int n = n0 + wn + nt * 16 + ln;
        float bv = bias[n];
#pragma unroll
        for (int mt = 0; mt < 4; ++mt) {
            int mb = m0 + wm + mt * 16 + q * 4;
#pragma unroll
            for (int r = 0; r < 4; ++r)
                C[(size_t)(mb + r) * N + n] = (OutT)(acc[mt][nt][r] + bv);
        }
    }
}

// ---------------------------------------------------------------------------
// In-place per-head L2 normalize: x / (||x||+1e-8), head dim 64.
// grid (4096, 2) -> (B*S rows / 4 waves, {Q,K}), 256 thr.
// ---------------------------------------------------------------------------
__global__ __launch_bounds__(256) void knorm(bf16_t* Q, bf16_t* K)
{
    const int tid = threadIdx.x;
    const int wave = tid >> 6, lane = tid & 63;
    bf16_t* T = blockIdx.y ? K : Q;
    size_t row = (size_t)blockIdx.x * 4 + wave;
    bf16_t* p = T + row * 1024 + lane * 16;
    bf16x8 v0 = *(bf16x8*)p, v1 = *(bf16x8*)(p + 8);
    float f[16];
#pragma unroll
    for (int i = 0; i < 8; ++i) { f[i] = (float)v0[i]; f[8 + i] = (float)v1[i]; }
    float ss = 0.f;
#pragma unroll
    for (int i = 0; i < 16; ++i) ss += f[i] * f[i];
    ss += __shfl_xor(ss, 1, 64);
    ss += __shfl_xor(ss, 2, 64);
    float sc = 1.0f / (sqrtf(ss) + 1e-8f);
    bf16x8 o0, o1;
#pragma unroll
    for (int i = 0; i < 8; ++i) {
        o0[i] = (bf16_t)(f[i] * sc);
        o1[i] = (bf16_t)(f[8 + i] * sc);
    }
    *(bf16x8*)p = o0;
    *(bf16x8*)(p + 8) = o1;
}

// ---------------------------------------------------------------------------
// K-side: Kp = relu(Khat*proj^T)+0.1, partial KV[f][d] & Ksum[f] per s-chunk.
// grid (64 bh, 4 chunks of 1024 s), 256 thr. Partials fp32 -> P[bh][c][n][f].
// n: 0..63 = d, 64 = Ksum (ones row in Vt), 65..79 = 0.
// ---------------------------------------------------------------------------
__global__ __launch_bounds__(256) void kside(
    const bf16_t* __restrict__ Khat, const bf16_t* __restrict__ V,
    const bf16_t* __restrict__ proj, float* __restrict__ P)
{
    __shared__ bf16_t KpT[256 * 72];  // [f][s], wave-private f-slices
    __shared__ bf16_t Vt[80 * 72];    // [n][s], shared
    const int tid = threadIdx.x;
    const int lane = tid & 63, wave = tid >> 6;
    const int q = lane >> 4, ln = lane & 15;
    const int bh = blockIdx.x, c = blockIdx.y;
    const int b = bh >> 4, h = bh & 15;

    const bf16_t* Kh = Khat + (size_t)b * 4096 * 1024 + h * 64;
    const bf16_t* Vh = V + (size_t)b * 4096 * 1024 + h * 64;
    const bf16_t* pr = proj + (size_t)h * 256 * 64;

    // constant Vt rows: 64 = ones (Ksum), 65..79 = zeros
    for (int i = tid; i < 16 * 72; i += 256) {
        int rr = i / 72, cc = i % 72;
        Vt[(64 + rr) * 72 + cc] = (rr == 0) ? (bf16_t)1.0f : (bf16_t)0.0f;
    }
    // preload this wave's proj f-slice [wave*64, +64)
    bf16x8 pf[4][2];
#pragma unroll
    for (int nt = 0; nt < 4; ++nt)
#pragma unroll
        for (int ks = 0; ks < 2; ++ks)
            pf[nt][ks] = *(const bf16x8*)&pr[(size_t)(wave * 64 + nt * 16 + ln) * 64 + ks * 32 + q * 8];

    f32x4 kv[4][5] = {};
    const int s_base = c * 1024;
    for (int st = 0; st < 16; ++st) {
        const int s0 = s_base + st * 64;
        // phase 1: features for s-tile (64) x this wave's 64 f
        f32x4 fa[4][4] = {};
#pragma unroll
        for (int ks = 0; ks < 2; ++ks)
#pragma unroll
            for (int mt = 0; mt < 4; ++mt) {
                bf16x8 a = *(const bf16x8*)&Kh[(size_t)(s0 + mt * 16 + ln) * 1024 + ks * 32 + q * 8];
#pragma unroll
                for (int nt = 0; nt < 4; ++nt)
                    fa[mt][nt] = MFMA16(a, pf[nt][ks], fa[mt][nt]);
            }
        __syncthreads();  // prev phase2 done reading Vt
        // Kp -> KpT[f][s] (relu+eps), packed 4-bf16 stores
#pragma unroll
        for (int mt = 0; mt < 4; ++mt)
#pragma unroll
            for (int nt = 0; nt < 4; ++nt) {
                bf16x4 kp;
#pragma unroll
                for (int r = 0; r < 4; ++r)
                    kp[r] = (bf16_t)(fmaxf(fa[mt][nt][r], 0.0f) + 0.1f);
                *(bf16x4*)&KpT[(wave * 64 + nt * 16 + ln) * 72 + mt * 16 + q * 4] = kp;
            }
        // stage V tile transposed: Vt[d][s]
        for (int j = tid; j < 512; j += 256) {
            int s = j >> 3, d0 = (j & 7) * 8;
            bf16x8 v = *(const bf16x8*)&Vh[(size_t)(s0 + s) * 1024 + d0];
#pragma unroll
            for (int e = 0; e < 8; ++e) Vt[(d0 + e) * 72 + s] = v[e];
        }
        __syncthreads();
        // phase 2: KV[f][n] += KpT * Vt  (k = s, 64)
#pragma unroll
        for (int ks = 0; ks < 2; ++ks)
#pragma unroll
            for (int mt = 0; mt < 4; ++mt) {
                bf16x8 a = *(const bf16x8*)&KpT[(wave * 64 + mt * 16 + ln) * 72 + ks * 32 + q * 8];
#pragma unroll
                for (int nt = 0; nt < 5; ++nt) {
                    bf16x8 bb = *(const bf16x8*)&Vt[(nt * 16 + ln) * 72 + ks * 32 + q * 8];
                    kv[mt][nt] = MFMA16(a, bb, kv[mt][nt]);
                }
            }
    }
    float* Pp = P + (size_t)(bh * 4 + c) * 80 * 256;
#pragma unroll
    for (int mt = 0; mt < 4; ++mt)
#pragma unroll
        for (int nt = 0; nt < 5; ++nt)
            *(f32x4*)&Pp[(size_t)(nt * 16 + ln) * 256 + wave * 64 + mt * 16 + q * 4] = kv[mt][nt];
}

// ---------------------------------------------------------------------------
// Reduce 4 chunk-partials -> KVt[bh][n(80)][f(256)] bf16. grid 5120, 256 thr.
// ---------------------------------------------------------------------------
__global__ __launch_bounds__(256) void kreduce(const float* __restrict__ P, bf16_t* __restrict__ KVt)
{
    size_t i = (size_t)blockIdx.x * 256 + threadIdx.x;
    int f = (int)(i & 255);
    int n = (int)((i >> 8) % 80);
    int bh = (int)(i / (256 * 80));
    const float* p = P + (size_t)bh * 4 * 80 * 256 + (size_t)n * 256 + f;
    float s = 0.f;
#pragma unroll
    for (int c = 0; c < 4; ++c) s += p[(size_t)c * 80 * 256];
    KVt[i] = (bf16_t)s;
}

// ---------------------------------------------------------------------------
// Q-side: Qp = relu(Qhat*proj^T)+0.1; out = (Qp*KV)/max(Qp*Ksum,1e-6).
// grid (64 bh, 32 s-tiles of 128), 256 thr. Barrier-free (wave-private LDS).
// ---------------------------------------------------------------------------
__global__ __launch_bounds__(256) void qside(
    const bf16_t* __restrict__ Qhat, const bf16_t* __restrict__ proj,
    const bf16_t* __restrict__ KVt, bf16_t* __restrict__ attn)
{
    __shared__ bf16_t Qp[128 * 136];  // [s][f-half], wave-private 32-row slices
    const int tid = threadIdx.x;
    const int lane = tid & 63, wave = tid >> 6;
    const int q = lane >> 4, ln = lane & 15;
    const int bh = blockIdx.x, stile = blockIdx.y;
    const int b = bh >> 4, h = bh & 15;
    const size_t bs0 = (size_t)b * 4096 + (size_t)stile * 128;

    const bf16_t* Qh = Qhat + bs0 * 1024 + h * 64;
    const bf16_t* pr = proj + (size_t)h * 256 * 64;
    const bf16_t* kv = KVt + (size_t)bh * 80 * 256;

    f32x4 oacc[2][5] = {};
    for (int fh = 0; fh < 2; ++fh) {
        f32x4 fa[2][8] = {};
#pragma unroll
        for (int ks = 0; ks < 2; ++ks) {
            bf16x8 bb[8];
#pragma unroll
            for (int nt = 0; nt < 8; ++nt)
                bb[nt] = *(const bf16x8*)&pr[(size_t)(fh * 128 + nt * 16 + ln) * 64 + ks * 32 + q * 8];
#pragma unroll
            for (int mt = 0; mt < 2; ++mt) {
                bf16x8 a = *(const bf16x8*)&Qh[(size_t)(wave * 32 + mt * 16 + ln) * 1024 + ks * 32 + q * 8];
#pragma unroll
                for (int nt = 0; nt < 8; ++nt)
                    fa[mt][nt] = MFMA16(a, bb[nt], fa[mt][nt]);
            }
        }
        // Qp -> LDS [s][f] (wave-private rows)
#pragma unroll
        for (int mt = 0; mt < 2; ++mt)
#pragma unroll
            for (int nt = 0; nt < 8; ++nt)
#pragma unroll
                for (int r = 0; r < 4; ++r)
                    Qp[(wave * 32 + mt * 16 + q * 4 + r) * 136 + nt * 16 + ln] =
                        (bf16_t)(fmaxf(fa[mt][nt][r], 0.0f) + 0.1f);
        // phase 2: accumulate over this f-half (k = 128)
#pragma unroll
        for (int ks = 0; ks < 4; ++ks) {
            bf16x8 a[2];
#pragma unroll
            for (int mt = 0; mt < 2; ++mt)
                a[mt] = *(const bf16x8*)&Qp[(wave * 32 + mt * 16 + ln) * 136 + ks * 32 + q * 8];
#pragma unroll
            for (int nt = 0; nt < 5; ++nt) {
                bf16x8 bb = *(const bf16x8*)&kv[(size_t)(nt * 16 + ln) * 256 + fh * 128 + ks * 32 + q * 8];
#pragma unroll
                for (int mt = 0; mt < 2; ++mt)
                    oacc[mt][nt] = MFMA16(a[mt], bb, oacc[mt][nt]);
            }
        }
    }
    bf16_t* Ap = attn + bs0 * 1024 + h * 64;
#pragma unroll
    for (int mt = 0; mt < 2; ++mt)
#pragma unroll
        for (int r = 0; r < 4; ++r) {
            float nrm = __shfl(oacc[mt][4][r], lane & 48, 64);  // quad's ln==0 lane holds n=64 col
            nrm = fmaxf(nrm, 1e-6f);
            int s_local = wave * 32 + mt * 16 + q * 4 + r;
#pragma unroll
            for (int nt = 0; nt < 4; ++nt) {
                float val = oacc[mt][nt][r] / nrm;
                Ap[(size_t)s_local * 1024 + nt * 16 + ln] = (bf16_t)val;
            }
        }
}

// ---------------------------------------------------------------------------
extern "C" void kernel_launch(void* const* d_in, const int* in_sizes, int n_in,
                              void* d_out, int out_size, void* d_ws, size_t ws_size,
                              hipStream_t stream)
{
    const float* x = (const float*)d_in[0];
    const float* Wq = (const float*)d_in[1];
    const float* bq = (const float*)d_in[2];
    const float* Wk = (const float*)d_in[3];
    const float* bk = (const float*)d_in[4];
    const float* Wv = (const float*)d_in[5];
    const float* bv = (const float*)d_in[6];
    const float* Wo = (const float*)d_in[7];
    const float* bo = (const float*)d_in[8];
    const float* proj = (const float*)d_in[9];

    char* ws = (char*)d_ws;
    bf16_t* WT = (bf16_t*)(ws);                      //  8 MiB (4x 1024^2 bf16)
    bf16_t* projb = (bf16_t*)(ws + (8ull << 20));    //  0.5 MiB
    bf16_t* KVt = (bf16_t*)(ws + (9ull << 20));      //  2.5 MiB
    bf16_t* Q = (bf16_t*)(ws + (12ull << 20));       // 32 MiB
    bf16_t* K = (bf16_t*)(ws + (44ull << 20));       // 32 MiB
    bf16_t* V = (bf16_t*)(ws + (76ull << 20));       // 32 MiB (reused as attn)
    bf16_t* xb = (bf16_t*)(ws + (108ull << 20));     // 32 MiB (reused as P)
    float* P = (float*)xb;                           // 20 MiB, xb dead by then
    bf16_t* attn = V;                                // V dead after kside
    float* out = (float*)d_out;

    castbf<<<8192, 256, 0, stream>>>(x, xb);
    castbf<<<128, 256, 0, stream>>>(proj, projb);
    ktrans<<<dim3(16, 16, 4), 256, 0, stream>>>(Wq, Wk, Wv, Wo, WT);
    gemm_bt<bf16_t><<<dim3(128, 8), 256, 0, stream>>>(xb, WT + 0ull * 1048576, bq, Q, 16384, 1024, 1024);
    gemm_bt<bf16_t><<<dim3(128, 8), 256, 0, stream>>>(xb, WT + 1ull * 1048576, bk, K, 16384, 1024, 1024);
    gemm_bt<bf16_t><<<dim3(128, 8), 256, 0, stream>>>(xb, WT + 2ull * 1048576, bv, V, 16384, 1024, 1024);
    knorm<<<dim3(4096, 2), 256, 0, stream>>>(Q, K);
    kside<<<dim3(64, 4), 256, 0, stream>>>(K, V, projb, P);
    kreduce<<<5120, 256, 0, stream>>>(P, KVt);
    qside<<<dim3(64, 32), 256, 0, stream>>>(Q, projb, KVt, attn);
    gemm_bt<float><<<dim3(128, 8), 256, 0, stream>>>(attn, WT + 3ull * 1048576, bo, out, 16384, 1024, 1024);
}